// Round 6
// baseline (243.667 us; speedup 1.0000x reference)
//
#include <hip/hip_runtime.h>
#include <cmath>

// Problem constants (B=1): x (1,4,64,128,128) f32
#define Cc 64
#define Hh 128
#define Ww 128
#define HW_ 16384
#define THW_ 65536
#define CHW_ 1048576
#define NT 27

typedef unsigned short ushort_t;
typedef _Float16 f16x2 __attribute__((ext_vector_type(2)));
typedef _Float16 f16x8 __attribute__((ext_vector_type(8)));
typedef __fp16 fp16x2_alt __attribute__((ext_vector_type(2)));
typedef float floatx4 __attribute__((ext_vector_type(4)));

union U32H2 { unsigned u; f16x2 h; };

static __device__ inline ushort_t f2h(float f) {
  union { _Float16 h; ushort_t u; } v;
  v.h = (_Float16)f;
  return v.u;
}

static __device__ inline unsigned pk2(float a) {
  union { fp16x2_alt h; unsigned u; } v;
  v.h = __builtin_amdgcn_cvt_pkrtz(a, a);
  return v.u;
}

#if defined(__has_builtin)
#if __has_builtin(__builtin_amdgcn_make_buffer_rsrc) && __has_builtin(__builtin_amdgcn_raw_buffer_load_b32)
#define USE_BUF 1
#endif
#endif
#ifndef USE_BUF
#define USE_BUF 0
#endif

struct XtBuf {
#if USE_BUF
  __amdgpu_buffer_rsrc_t r;
#else
  const unsigned* p;
#endif
};

static __device__ inline XtBuf mkbuf(const ushort_t* xt) {
  XtBuf b;
#if USE_BUF
  b.r = __builtin_amdgcn_make_buffer_rsrc((void*)xt, (short)0, 8388608, 0x00020000);
#else
  b.p = (const unsigned*)xt;
#endif
  return b;
}

static __device__ inline unsigned xload(const XtBuf& b, unsigned voff) {
#if USE_BUF
  return (unsigned)__builtin_amdgcn_raw_buffer_load_b32(b.r, (int)voff, 0, 0);
#else
  return b.p[voff >> 2];
#endif
}

// ws layout (floats):
//   off    : [0, 5308416)           81 * 65536 f32
//   xt     : [5308416, +2097152)    x -> [t][h][w][c] f16 (4194304 ushorts)
//   wfrag  : [7405568, +55296)      deform weight B-frags, 110592 f16
//   w2frag : [7460864, +82944)      offconv weight B-frags, 165888 f16

__global__ __launch_bounds__(256) void prep(
    const float* __restrict__ offset_w,
    const float* __restrict__ weight,
    ushort_t* __restrict__ w2frag,
    ushort_t* __restrict__ wfrag)
{
  int e = blockIdx.x * 256 + threadIdx.x;
  if (e < 165888) {   // offconv: 27 taps x 6 oc-tiles x 2 khalf x 64 lanes x 8
    int j = e & 7, ln = (e >> 3) & 63, kh2 = (e >> 9) & 1, r = e >> 10;
    int ot = r % 6, k = r / 6;
    int oc = ot * 16 + (ln & 15);
    int c  = kh2 * 32 + (ln >> 4) * 8 + j;
    float v = (oc < 81) ? offset_w[(oc * 64 + c) * 27 + k] : 0.f;
    w2frag[e] = f2h(v);
  }
  if (e < 110592) {   // deform: 27 taps x 4 oc-tiles x 2 khalf x 64 lanes x 8
    int j = e & 7, ln = (e >> 3) & 63, kh2 = (e >> 9) & 1, r = e >> 10;
    int ot = r & 3, k = r >> 2;
    int o = ot * 16 + (ln & 15);
    int c = kh2 * 32 + (ln >> 4) * 8 + j;
    wfrag[e] = f2h(weight[(o * 64 + c) * 27 + k]);
  }
}

__global__ __launch_bounds__(256) void transpose_x(
    const float* __restrict__ x, ushort_t* __restrict__ xt)
{
  __shared__ float tile[64][65];
  int b = blockIdx.x;
  int wblk = b & 1;
  int th = b >> 1;
  int h = th & 127;
  int t = th >> 7;
  int w0 = wblk * 64;
  int lane = threadIdx.x & 63;
  int quad = threadIdx.x >> 6;
  #pragma unroll
  for (int cc = 0; cc < 16; ++cc) {
    int c = cc * 4 + quad;
    tile[c][lane] = x[t * CHW_ + c * HW_ + h * Ww + w0 + lane];
  }
  __syncthreads();
  #pragma unroll
  for (int ww = 0; ww < 16; ++ww) {
    int w = ww * 4 + quad;
    xt[(size_t)(t * HW_ + h * Ww + w0 + w) * 64 + lane] = f2h(tile[lane][w]);
  }
}

// Offset conv, c-split: block = 32 positions; wave = (pos-group 16, ch-half 32).
// Grid 2048 -> 8 blocks/CU -> 8 waves/SIMD. K=32 MFMA per oc-tile per tap.
// Pair-reduce partial acc (ch-halves) through LDS at the end.
__global__ __launch_bounds__(256, 8) void offconv(
    const ushort_t* __restrict__ xt,
    const ushort_t* __restrict__ w2frag,
    const float* __restrict__ ob,
    float* __restrict__ off)
{
  __shared__ __align__(16) char lds[13056];   // S: 4 x 1280 | Dbuf [96][34] f32
  float* Dbuf = (float*)lds;
  int lane = threadIdx.x & 63;
  int wavei = __builtin_amdgcn_readfirstlane(threadIdx.x >> 6);
  int pg = wavei >> 1;          // position group (16 pos)
  int chh = wavei & 1;          // channel half
  int quad = lane >> 4;
  int m16 = lane & 15;
  int g = lane >> 4;            // pos-in-batch for gather (0..3)
  int c2 = lane & 15;           // channel-pair (32 ch per wave)
  int p0 = blockIdx.x * 32;
  int t = p0 >> 14;
  int h = (p0 >> 7) & 127;
  int w0 = p0 & 127;
  char* Sb = lds + wavei * 1280;   // [16 rows][80 B], wave-local
  unsigned lanebyte = (unsigned)(chh * 64 + c2 * 4);
  XtBuf xb = mkbuf(xt);

  floatx4 acc[6];
  #pragma unroll
  for (int i = 0; i < 6; ++i) acc[i] = (floatx4){0.f, 0.f, 0.f, 0.f};

  unsigned pd[4];
  auto issue = [&](int k) {
    int kt = k / 9, kh = (k / 3) % 3, kw = k % 3;
    int tsc = min(max(t + kt - 1, 0), 3);
    int hsc = min(max(h + kh - 1, 0), 127);
    int sbase = tsc * HW_ + hsc * Ww;
    #pragma unroll
    for (int bq = 0; bq < 4; ++bq) {
      int prow = bq * 4 + g;
      int wc = w0 + pg * 16 + prow + kw - 1;
      int wcc = min(max(wc, 0), 127);
      pd[bq] = xload(xb, ((unsigned)(sbase + wcc) << 7) + lanebyte);
    }
  };

  issue(0);
  #pragma unroll 1
  for (int k = 0; k < NT; ++k) {
    int kt = k / 9, kh = (k / 3) % 3, kw = k % 3;
    bool rowok = ((unsigned)(t + kt - 1) < 4u) && ((unsigned)(h + kh - 1) < 128u);
    #pragma unroll
    for (int bq = 0; bq < 4; ++bq) {
      int prow = bq * 4 + g;
      int wc = w0 + pg * 16 + prow + kw - 1;
      bool ok = rowok && ((unsigned)wc < 128u);
      *(unsigned*)(Sb + prow * 80 + c2 * 4) = ok ? pd[bq] : 0u;
    }
    issue(k + 1 < NT ? k + 1 : NT - 1);
    f16x8 af = *(const f16x8*)(Sb + m16 * 80 + quad * 16);
    #pragma unroll
    for (int ot = 0; ot < 6; ++ot) {
      const ushort_t* wb = w2frag + (size_t)((k * 6 + ot) * 2 + chh) * 512 + lane * 8;
      f16x8 bf = *(const f16x8*)wb;
      acc[ot] = __builtin_amdgcn_mfma_f32_16x16x32_f16(af, bf, acc[ot], 0, 0, 0);
    }
  }
  __syncthreads();   // S dead; Dbuf aliases it
  if (chh == 0) {
    #pragma unroll
    for (int ot = 0; ot < 6; ++ot)
      #pragma unroll
      for (int r = 0; r < 4; ++r)
        Dbuf[(ot * 16 + m16) * 34 + pg * 16 + quad * 4 + r] = acc[ot][r];
  }
  __syncthreads();
  if (chh == 1) {
    #pragma unroll
    for (int ot = 0; ot < 6; ++ot)
      #pragma unroll
      for (int r = 0; r < 4; ++r)
        Dbuf[(ot * 16 + m16) * 34 + pg * 16 + quad * 4 + r] += acc[ot][r];
  }
  __syncthreads();
  for (int i = threadIdx.x; i < 81 * 32; i += 256) {
    int oc = i >> 5, p = i & 31;
    off[(size_t)oc * THW_ + p0 + p] = Dbuf[oc * 34 + p] + ob[oc];
  }
}

// Deformable sample + MFMA, c-split: block = 32 pos; wave = (pos-group, ch-half).
// Meta (sites+weights) per wave in wave-local LDS; tap loop barrier-free.
__global__ __launch_bounds__(256, 8) void deform(
    const float* __restrict__ x,
    const ushort_t* __restrict__ xt,
    const float* __restrict__ off,
    const ushort_t* __restrict__ wfrag,
    const float* __restrict__ gamma,
    float* __restrict__ out)
{
  __shared__ __align__(16) char lds[9216];    // 4 x (S 1280 + mt 1024) | Dbuf [64][34]
  float* Dbuf = (float*)lds;
  int lane = threadIdx.x & 63;
  int wavei = __builtin_amdgcn_readfirstlane(threadIdx.x >> 6);
  int pg = wavei >> 1;
  int chh = wavei & 1;
  int quad = lane >> 4;
  int m16 = lane & 15;
  int g = lane >> 4;
  int c2 = lane & 15;
  int p0 = blockIdx.x * 32;
  int t = p0 >> 14;
  int h = (p0 >> 7) & 127;
  int w0 = p0 & 127;
  char* Sb = lds + wavei * 2304;              // [16 rows][80 B]
  char* Mt = Sb + 1280;                       // [16 pos][8 corners][{site,w2} 8 B]
  unsigned lanebyte = (unsigned)(chh * 64 + c2 * 4);
  XtBuf xb = mkbuf(xt);

  floatx4 acc[4];
  #pragma unroll
  for (int i = 0; i < 4; ++i) acc[i] = (floatx4){0.f, 0.f, 0.f, 0.f};

  int pl = pg * 16 + m16;       // position within block (meta role)
  int pm = p0 + pl;             // global position
  int aq = quad >> 1, bq = quad & 1;
  const float* offT = off + pm;

  float dt_c = offT[(size_t)(0 * NT + 0) * THW_];
  float dh_c = offT[(size_t)(1 * NT + 0) * THW_];
  float dw_c = offT[(size_t)(2 * NT + 0) * THW_];

  #pragma unroll 1
  for (int k = 0; k < NT; ++k) {
    int kn = (k + 1 < NT) ? k + 1 : NT - 1;
    float dt_n = offT[(size_t)(0 * NT + kn) * THW_];
    float dh_n = offT[(size_t)(1 * NT + kn) * THW_];
    float dw_n = offT[(size_t)(2 * NT + kn) * THW_];

    int kt = k / 9, kh = (k / 3) % 3, kw = k % 3;
    // --- meta: lane handles position pl, (t,h)-corner (aq,bq), both w-corners
    float tf = (float)(t + kt - 1) + dt_c;
    float hf = (float)(h + kh - 1) + dh_c;
    float wf = (float)(w0 + pl + kw - 1) + dw_c;
    float tF = floorf(tf), hF = floorf(hf), wF = floorf(wf);
    float lt = tf - tF, lh_ = hf - hF, lw_ = wf - wF;
    int t0 = (int)tF, h0 = (int)hF, wq_ = (int)wF;
    int ti = t0 + aq;
    float wt_ = (aq ? lt : 1.f - lt) * (((unsigned)ti < 4u) ? 1.f : 0.f);
    int tic = min(max(ti, 0), 3);
    int hi = h0 + bq;
    float wh_ = (bq ? lh_ : 1.f - lh_) * (((unsigned)hi < 128u) ? 1.f : 0.f);
    int hic = min(max(hi, 0), 127);
    int base2 = tic * HW_ + hic * Ww;
    float bw = wt_ * wh_;
    int wi0 = wq_;
    float ww0 = (1.f - lw_) * (((unsigned)wi0 < 128u) ? 1.f : 0.f);
    int wi0c = min(max(wi0, 0), 127);
    int wi1 = wq_ + 1;
    float ww1 = lw_ * (((unsigned)wi1 < 128u) ? 1.f : 0.f);
    int wi1c = min(max(wi1, 0), 127);
    uint4 me;
    me.x = (unsigned)(base2 + wi0c) << 7;
    me.y = pk2(bw * ww0);
    me.z = (unsigned)(base2 + wi1c) << 7;
    me.w = pk2(bw * ww1);
    *(uint4*)(Mt + m16 * 64 + quad * 16) = me;

    // --- gather: 4 batches of 4 positions; lane = (pos-in-batch, ch-pair)
    #pragma unroll
    for (int b2 = 0; b2 < 4; ++b2) {
      int prow = b2 * 4 + g;
      const uint4* mrow = (const uint4*)(Mt + prow * 64);
      uint4 m01 = mrow[0], m23 = mrow[1], m45 = mrow[2], m67 = mrow[3];
      unsigned d0 = xload(xb, m01.x + lanebyte);
      unsigned d1 = xload(xb, m01.z + lanebyte);
      unsigned d2 = xload(xb, m23.x + lanebyte);
      unsigned d3 = xload(xb, m23.z + lanebyte);
      unsigned d4 = xload(xb, m45.x + lanebyte);
      unsigned d5 = xload(xb, m45.z + lanebyte);
      unsigned d6 = xload(xb, m67.x + lanebyte);
      unsigned d7 = xload(xb, m67.z + lanebyte);
      U32H2 z; z.u = 0;
      f16x2 a2l = z.h, a2h = z.h;
      U32H2 du, wu;
      du.u = d0; wu.u = m01.y; a2l += wu.h * du.h;
      du.u = d1; wu.u = m01.w; a2h += wu.h * du.h;
      du.u = d2; wu.u = m23.y; a2l += wu.h * du.h;
      du.u = d3; wu.u = m23.w; a2h += wu.h * du.h;
      du.u = d4; wu.u = m45.y; a2l += wu.h * du.h;
      du.u = d5; wu.u = m45.w; a2h += wu.h * du.h;
      du.u = d6; wu.u = m67.y; a2l += wu.h * du.h;
      du.u = d7; wu.u = m67.w; a2h += wu.h * du.h;
      U32H2 res;
      res.h = a2l + a2h;
      *(unsigned*)(Sb + prow * 80 + c2 * 4) = res.u;
    }
    // --- MFMA: K=32 (this wave's channel half)
    f16x8 af = *(const f16x8*)(Sb + m16 * 80 + quad * 16);
    #pragma unroll
    for (int ot = 0; ot < 4; ++ot) {
      const ushort_t* wb = wfrag + (size_t)((k * 4 + ot) * 2 + chh) * 512 + lane * 8;
      f16x8 bf = *(const f16x8*)wb;
      acc[ot] = __builtin_amdgcn_mfma_f32_16x16x32_f16(af, bf, acc[ot], 0, 0, 0);
    }
    dt_c = dt_n; dh_c = dh_n; dw_c = dw_n;
  }
  __syncthreads();   // S/meta dead; Dbuf aliases them
  if (chh == 0) {
    #pragma unroll
    for (int ot = 0; ot < 4; ++ot)
      #pragma unroll
      for (int r = 0; r < 4; ++r)
        Dbuf[(ot * 16 + m16) * 34 + pg * 16 + quad * 4 + r] = acc[ot][r];
  }
  __syncthreads();
  if (chh == 1) {
    #pragma unroll
    for (int ot = 0; ot < 4; ++ot)
      #pragma unroll
      for (int r = 0; r < 4; ++r)
        Dbuf[(ot * 16 + m16) * 34 + pg * 16 + quad * 4 + r] += acc[ot][r];
  }
  __syncthreads();
  float gm = gamma[0];
  for (int i = threadIdx.x; i < 64 * 32; i += 256) {
    int oc = i >> 5, p = i & 31;
    size_t oi = (size_t)t * CHW_ + (size_t)oc * HW_ + (size_t)h * Ww + w0 + p;
    out[oi] = fmaf(gm, Dbuf[oc * 34 + p], x[oi]);
  }
}

extern "C" void kernel_launch(void* const* d_in, const int* in_sizes, int n_in,
                              void* d_out, int out_size, void* d_ws, size_t ws_size,
                              hipStream_t stream) {
  (void)in_sizes; (void)n_in; (void)out_size; (void)ws_size;
  const float* x        = (const float*)d_in[0];
  const float* offset_w = (const float*)d_in[1];
  const float* offset_b = (const float*)d_in[2];
  const float* weight   = (const float*)d_in[3];
  const float* gamma    = (const float*)d_in[4];
  float* out = (float*)d_out;
  float* wsf = (float*)d_ws;
  float*    off    = wsf;                               // 5308416 f32
  ushort_t* xt     = (ushort_t*)(wsf + 5308416);        // 4194304 f16
  ushort_t* wfrag  = (ushort_t*)(wsf + 7405568);        // 110592 f16
  ushort_t* w2frag = (ushort_t*)(wsf + 7460864);        // 165888 f16

  hipLaunchKernelGGL(prep, dim3(648), dim3(256), 0, stream,
                     offset_w, weight, w2frag, wfrag);
  hipLaunchKernelGGL(transpose_x, dim3(1024), dim3(256), 0, stream, x, xt);
  hipLaunchKernelGGL(offconv, dim3(2048), dim3(256), 0, stream,
                     xt, w2frag, offset_b, off);
  hipLaunchKernelGGL(deform, dim3(2048), dim3(256), 0, stream,
                     x, xt, off, wfrag, gamma, out);
}